// Round 16
// baseline (174.412 us; speedup 1.0000x reference)
//
#include <hip/hip_runtime.h>
#include <hip/hip_bf16.h>
#include <math.h>

typedef float f32x4 __attribute__((ext_vector_type(4)));
typedef __bf16 bf16x8 __attribute__((ext_vector_type(8)));
typedef _Float16 f16;
typedef _Float16 f16x4 __attribute__((ext_vector_type(4)));
typedef unsigned short ushort;

#define NROWS 8192
#define HID 256
#define NCOL 4096
#define NSTEPS 20

static __device__ inline float bf2f(ushort u) {
    union { unsigned int i; float f; } c; c.i = ((unsigned int)u) << 16; return c.f;
}
static __device__ inline ushort f2bf(float x) {
    __hip_bfloat16 h = __float2bfloat16(x);
    union { __hip_bfloat16 h; ushort u; } c; c.h = h; return c.u;
}
static __device__ inline float fast_tanh(float x) {
    float e = __expf(2.0f * x);
    return 1.0f - 2.0f / (e + 1.0f);
}
static __device__ inline void gload_lds16(const void* g, void* l) {
    __builtin_amdgcn_global_load_lds(
        (const __attribute__((address_space(1))) void*)g,
        (__attribute__((address_space(3))) void*)l, 16, 0, 0);
}

// ---------------------------------------------------------------- prep: W2 -> bf16 hi|lo, b2s, W0t, W1t
__global__ __launch_bounds__(256) void prep_kernel(
    const float* __restrict__ W2, const float* __restrict__ b2,
    const float* __restrict__ W0, const float* __restrict__ W1,
    ushort* __restrict__ Bext, float* __restrict__ b2s,
    float* __restrict__ W0t, float* __restrict__ W1t)
{
    const int r = blockIdx.x, t = threadIdx.x;
    float v = W2[(size_t)(r + 1) * 256 + t];
    ushort hi = f2bf(v);
    float lo = v - bf2f(hi);
    Bext[(size_t)r * 512 + t] = hi;
    Bext[(size_t)r * 512 + 256 + t] = f2bf(lo);
    if (t == 0) b2s[r] = b2[r + 1];
    if (r < 256) W1t[r * 256 + t] = W1[t * 256 + r];
    if (r < 65)  W0t[r * 256 + t] = W0[t * 65 + r];
}

// ---------------------------------------------------------------- MLP layers 0+1 (+ fused kl_target)
__global__ __launch_bounds__(256) void mlp01_kernel(
    const float* __restrict__ x, const float* __restrict__ klb,
    const float* __restrict__ W0t, const float* __restrict__ b0,
    const float* __restrict__ W1t, const float* __restrict__ b1,
    const float* __restrict__ W2, const float* __restrict__ b2,
    const int* __restrict__ AL,
    ushort* __restrict__ t_ext, float* __restrict__ kt)
{
    __shared__ float xk[16][66];
    __shared__ float h0[16][HID];
    __shared__ float ktred[16][4];
    const int tid = threadIdx.x;
    const int lane = tid & 63, w = tid >> 6;
    const int r0 = blockIdx.x * 16;

    for (int f = tid; f < 16 * 64; f += 256) {
        int r = f >> 6, k = f & 63;
        xk[r][k] = x[(size_t)(r0 + r) * 64 + k];
    }
    if (tid < 16) xk[tid][64] = klb[r0 + tid];
    __syncthreads();

    {
        float acc[16];
        float bb = b0[tid];
        #pragma unroll
        for (int r = 0; r < 16; r++) acc[r] = bb;
        for (int k = 0; k < 65; k++) {
            float wv = W0t[k * 256 + tid];
            #pragma unroll
            for (int r = 0; r < 16; r++) acc[r] = fmaf(wv, xk[r][k], acc[r]);
        }
        #pragma unroll
        for (int r = 0; r < 16; r++) h0[r][tid] = fast_tanh(acc[r]);
    }
    __syncthreads();
    {
        float acc[16];
        float bb = b1[tid];
        #pragma unroll
        for (int r = 0; r < 16; r++) acc[r] = bb;
        for (int k = 0; k < HID; k++) {
            float wv = W1t[k * 256 + tid];
            #pragma unroll
            for (int r = 0; r < 16; r++) acc[r] = fmaf(wv, h0[r][k], acc[r]);
        }
        const float w2v = W2[tid];   // W2 row 0
        __syncthreads();
        #pragma unroll
        for (int r = 0; r < 16; r++) {
            float v = fast_tanh(acc[r]);
            ushort hi = f2bf(v);
            float lo = v - bf2f(hi);
            size_t base = (size_t)(r0 + r) * 512;
            t_ext[base + tid] = hi;
            t_ext[base + 256 + tid] = f2bf(lo);
            float p = v * w2v;
            #pragma unroll
            for (int off = 1; off < 64; off <<= 1) p += __shfl_xor(p, off);
            if (lane == 0) ktred[r][w] = p;
        }
        __syncthreads();
        if (tid < 16) {
            float accv = ktred[tid][0] + ktred[tid][1] + ktred[tid][2] + ktred[tid][3];
            float z = accv + b2[0] - logf((float)AL[0]);
            float sg = 1.0f / (1.0f + expf(-z));
            kt[r0 + tid] = sg * klb[r0 + tid] + 1e-6f;
        }
    }
}

// ---------------------------------------------------------------- layer-2 GEMM (split-bf16 MFMA), f16 out, XCD swizzle
__global__ __launch_bounds__(256) void gemm2_mfma(
    const ushort* __restrict__ Aext, const ushort* __restrict__ Bext,
    const float* __restrict__ b2s, f16* __restrict__ h2f)
{
    __shared__ ushort As[128 * 64];
    __shared__ ushort Bs[128 * 64];
    const int tid = threadIdx.x;
    const int lane = tid & 63, w = tid >> 6;
    // XCD-aware bijective swizzle: nwg = 2048, 8 XCDs, 256 blocks each
    const int bid = blockIdx.y * 32 + blockIdx.x;
    const int swz = (bid & 7) * 256 + (bid >> 3);
    const int m0 = (swz >> 5) * 128, c0 = (swz & 31) * 128;
    const int wm = w & 1, wn = w >> 1;

    f32x4 acc[4][4];
    #pragma unroll
    for (int i = 0; i < 4; i++)
        #pragma unroll
        for (int j = 0; j < 4; j++) acc[i][j] = (f32x4){0.f, 0.f, 0.f, 0.f};

    int sg_row[4], sg_c[4];
    #pragma unroll
    for (int s = 0; s < 4; s++) {
        int idx = (s * 4 + w) * 512 + lane * 8;
        int row = idx >> 6;
        int cp = (idx >> 3) & 7;
        sg_row[s] = row;
        sg_c[s] = cp ^ (row & 7);
    }

    for (int kt = 0; kt < 8; kt++) {
        const int k0 = kt * 64;
        #pragma unroll
        for (int s = 0; s < 4; s++) {
            gload_lds16(&Aext[(size_t)(m0 + sg_row[s]) * 512 + k0 + sg_c[s] * 8],
                        &As[(s * 4 + w) * 512]);
            gload_lds16(&Bext[(size_t)(c0 + sg_row[s]) * 512 + k0 + sg_c[s] * 8],
                        &Bs[(s * 4 + w) * 512]);
        }
        __syncthreads();
        #pragma unroll
        for (int kk = 0; kk < 2; kk++) {
            const int cA = kk * 4 + (lane >> 4);
            bf16x8 af[4], bfr[4];
            #pragma unroll
            for (int i = 0; i < 4; i++) {
                int mr = wm * 64 + i * 16 + (lane & 15);
                af[i] = *(const bf16x8*)&As[mr * 64 + ((cA ^ (mr & 7)) * 8)];
                int nr = wn * 64 + i * 16 + (lane & 15);
                bfr[i] = *(const bf16x8*)&Bs[nr * 64 + ((cA ^ (nr & 7)) * 8)];
            }
            #pragma unroll
            for (int i = 0; i < 4; i++)
                #pragma unroll
                for (int j = 0; j < 4; j++)
                    acc[i][j] = __builtin_amdgcn_mfma_f32_16x16x32_bf16(
                        af[i], bfr[j], acc[i][j], 0, 0, 0);
        }
        __syncthreads();
    }

    const int colb = c0 + wn * 64 + (lane & 15);
    #pragma unroll
    for (int j = 0; j < 4; j++) {
        float bias = b2s[colb + j * 16];
        #pragma unroll
        for (int i = 0; i < 4; i++) {
            int rr = m0 + wm * 64 + i * 16 + (lane >> 4) * 4;
            #pragma unroll
            for (int q = 0; q < 4; q++)
                h2f[(size_t)(rr + q) * 4096 + colb + j * 16] = (f16)(acc[i][j][q] + bias);
        }
    }
}

// ---------------------------------------------------------------- solver: FOUR WAVES PER ROW, 16 elems/thread (f16)
__global__ __launch_bounds__(256) void solve256(
    float* __restrict__ out, const f16* __restrict__ h2f,
    const float* __restrict__ logb, const float* __restrict__ ktarr)
{
    __shared__ float red[16];
    const int tid = threadIdx.x;
    const int lane = tid & 63, w = tid >> 6;
    const int r = blockIdx.x;

    const f16* hrow = h2f + (size_t)r * 4096;
    const float* brow = logb + (size_t)r * 4096;

    f16x4 h4[4];
    f32x4 bv4[4];
    #pragma unroll
    for (int c = 0; c < 4; c++) {
        h4[c] = *(const f16x4*)&hrow[c * 1024 + tid * 4];
        bv4[c] = *(const f32x4*)&brow[c * 1024 + tid * 4];
    }

    float e[16];
    float s = 0.0f, sav = 0.0f;
    #pragma unroll
    for (int c = 0; c < 4; c++)
        #pragma unroll
        for (int j = 0; j < 4; j++) {
            int m = c * 4 + j;
            float av = (float)h4[c][j];
            e[m] = __expf(av + bv4[c][j]);
            s += e[m];
            sav = fmaf(e[m], av, sav);
        }
    #pragma unroll
    for (int off = 1; off < 64; off <<= 1) {
        s   += __shfl_xor(s, off);
        sav += __shfl_xor(sav, off);
    }
    if (lane == 0) { red[w * 2] = s; red[w * 2 + 1] = sav; }
    __syncthreads();
    s   = red[0] + red[2] + red[4] + red[6];
    sav = red[1] + red[3] + red[5] + red[7];

    const float k = ktarr[r];
    const float lns = __logf(s);
    const float inv = 1.0f / s;
    const float kl1 = fmaf(sav, inv, -lns);       // KL(a||b) at alpha=1

    float* orow = out + (size_t)r * 4096;

    if (k >= kl1) {  // fast path: alpha=1, no more barriers
        #pragma unroll
        for (int c = 0; c < 4; c++) {
            f32x4 o;
            #pragma unroll
            for (int j = 0; j < 4; j++) o[j] = e[c * 4 + j] * inv;
            *(f32x4*)&orow[c * 1024 + tid * 4] = o;
        }
        if (tid == 0) {
            float d = kl1 - k;
            out[(size_t)NROWS * NCOL + r] = d * d;
        }
        return;
    }

    // ---------- slow path (~few % of rows) ----------
    float eb[16];
    float c2 = 0.0f, c3 = 0.0f, seb = 0.0f, samv = 0.0f;
    #pragma unroll
    for (int c = 0; c < 4; c++)
        #pragma unroll
        for (int j = 0; j < 4; j++) {
            int m = c * 4 + j;
            float b = bv4[c][j];
            float ebv = __expf(b);
            eb[m] = ebv;
            float a = fmaf(e[m], inv, -ebv);   // amb = ea - eb
            float av = (float)h4[c][j];
            e[m] = a;                          // e[] now holds amb
            c2  = fmaf(ebv, b, c2);            // sum eb*lb
            c3  = fmaf(a, b, c3);              // sum amb*lb
            seb += ebv;
            samv = fmaf(a, av, samv);          // sum amb*av
        }
    #pragma unroll
    for (int off = 1; off < 64; off <<= 1) {
        c2   += __shfl_xor(c2, off);
        c3   += __shfl_xor(c3, off);
        seb  += __shfl_xor(seb, off);
        samv += __shfl_xor(samv, off);
    }
    __syncthreads();
    if (lane == 0) {
        red[w * 4 + 0] = c2;  red[w * 4 + 1] = c3;
        red[w * 4 + 2] = seb; red[w * 4 + 3] = samv;
    }
    __syncthreads();
    c2   = red[0] + red[4] + red[8]  + red[12];
    c3   = red[1] + red[5] + red[9]  + red[13];
    seb  = red[2] + red[6] + red[10] + red[14];
    samv = red[3] + red[7] + red[11] + red[15];

    const float C2 = c2;
    const float C3 = c3;
    const float C4 = (1.0f - seb) - C3;

    float skl = kl1, a_eval = 1.0f;
    float bot = 0.0f, top = 1.0f;
    float d1 = samv - lns * (1.0f - seb) + C4;
    float alpha = fminf(0.5f, fmaxf(1.0f / 16.0f,
                        1.0f + (k - kl1) / (d1 + 1e-12f)));

    for (int it = 1; it < NSTEPS; it++) {
        a_eval = alpha;
        float kacc = 0.0f, dacc = 0.0f;
        #pragma unroll
        for (int m = 0; m < 16; m++) {
            float xv = fmaf(alpha, e[m], eb[m]);
            float lx = __logf(xv);
            kacc = fmaf(xv, lx, kacc);
            dacc = fmaf(e[m], lx, dacc);
        }
        #pragma unroll
        for (int off = 1; off < 64; off <<= 1) {
            kacc += __shfl_xor(kacc, off);
            dacc += __shfl_xor(dacc, off);
        }
        __syncthreads();
        if (lane == 0) { red[w * 2 + 0] = kacc; red[w * 2 + 1] = dacc; }
        __syncthreads();
        kacc = red[0] + red[2] + red[4] + red[6];
        dacc = red[1] + red[3] + red[5] + red[7];

        float klc = kacc - C2 - alpha * C3;
        float dc  = dacc + C4;
        skl = klc;

        bot = (k >= klc) ? alpha : bot;
        top = (k <= klc) ? alpha : top;
        float delta = (k - klc) / (dc + 1e-12f);
        float lo = bot * (15.0f / 16.0f) + top * (1.0f / 16.0f);
        float hi = 0.5f * (bot + top);
        alpha = fminf(hi, fmaxf(lo, alpha + delta));
        if (top - bot < 1e-6f) break;
    }

    if (alpha != a_eval) {
        float kacc = 0.0f;
        #pragma unroll
        for (int m = 0; m < 16; m++) {
            float xv = fmaf(alpha, e[m], eb[m]);
            kacc = fmaf(xv, __logf(xv), kacc);
        }
        #pragma unroll
        for (int off = 1; off < 64; off <<= 1) kacc += __shfl_xor(kacc, off);
        __syncthreads();
        if (lane == 0) red[w] = kacc;
        __syncthreads();
        kacc = red[0] + red[1] + red[2] + red[3];
        skl = kacc - C2 - alpha * C3;
    }

    const float spx = fmaf(alpha, 1.0f - seb, seb);
    const float invs = 1.0f / spx;
    #pragma unroll
    for (int c = 0; c < 4; c++) {
        f32x4 o;
        #pragma unroll
        for (int j = 0; j < 4; j++)
            o[j] = fmaf(alpha, e[c * 4 + j], eb[c * 4 + j]) * invs;
        *(f32x4*)&orow[c * 1024 + tid * 4] = o;
    }
    if (tid == 0) {
        float d = skl - k;
        out[(size_t)NROWS * NCOL + r] = d * d;
    }
}

extern "C" void kernel_launch(void* const* d_in, const int* in_sizes, int n_in,
                              void* d_out, int out_size, void* d_ws, size_t ws_size,
                              hipStream_t stream)
{
    const float* x    = (const float*)d_in[0];
    const float* klb  = (const float*)d_in[1];
    const float* logb = (const float*)d_in[2];
    const float* W0   = (const float*)d_in[3];
    const float* b0   = (const float*)d_in[4];
    const float* W1   = (const float*)d_in[5];
    const float* b1   = (const float*)d_in[6];
    const float* W2   = (const float*)d_in[7];
    const float* b2   = (const float*)d_in[8];
    const int*   AL   = (const int*)d_in[9];
    float* out = (float*)d_out;

    const size_t MB = 1048576ull;
    const size_t KB = 1024ull;
    char* p = (char*)d_ws;
    ushort* tws  = (ushort*)(p);                      // Aext: 8 MB
    ushort* Bext = (ushort*)(p + 8 * MB);             // 4 MB
    float*  kt   = (float*) (p + 12 * MB);            // 32 KB
    float*  b2s  = (float*) (p + 12 * MB + 64 * KB);  // 16 KB
    float*  W0t  = (float*) (p + 12 * MB + 128 * KB); // 66.6 KB
    float*  W1t  = (float*) (p + 12 * MB + 256 * KB); // 256 KB
    f16*    h2f  = (f16*)   (p + 16 * MB);            // 64 MB

    hipLaunchKernelGGL(prep_kernel, dim3(4096), dim3(256), 0, stream,
                       W2, b2, W0, W1, Bext, b2s, W0t, W1t);
    hipLaunchKernelGGL(mlp01_kernel, dim3(512), dim3(256), 0, stream,
                       x, klb, W0t, b0, W1t, b1, W2, b2, AL, tws, kt);
    hipLaunchKernelGGL(gemm2_mfma, dim3(32, 64), dim3(256), 0, stream, tws, Bext, b2s, h2f);
    hipLaunchKernelGGL(solve256, dim3(8192), dim3(256), 0, stream, out, h2f, logb, kt);
}

// Round 17
// 156.697 us; speedup vs baseline: 1.1131x; 1.1131x over previous
//
#include <hip/hip_runtime.h>
#include <hip/hip_bf16.h>
#include <math.h>

typedef float f32x4 __attribute__((ext_vector_type(4)));
typedef __bf16 bf16x8 __attribute__((ext_vector_type(8)));
typedef _Float16 f16;
typedef _Float16 f16x4 __attribute__((ext_vector_type(4)));
typedef unsigned short ushort;

#define NROWS 8192
#define HID 256
#define NCOL 4096
#define NSTEPS 20

static __device__ inline float bf2f(ushort u) {
    union { unsigned int i; float f; } c; c.i = ((unsigned int)u) << 16; return c.f;
}
static __device__ inline ushort f2bf(float x) {
    __hip_bfloat16 h = __float2bfloat16(x);
    union { __hip_bfloat16 h; ushort u; } c; c.h = h; return c.u;
}
static __device__ inline float fast_tanh(float x) {
    float e = __expf(2.0f * x);
    return 1.0f - 2.0f / (e + 1.0f);
}
static __device__ inline void gload_lds16(const void* g, void* l) {
    __builtin_amdgcn_global_load_lds(
        (const __attribute__((address_space(1))) void*)g,
        (__attribute__((address_space(3))) void*)l, 16, 0, 0);
}

// ---------------------------------------------------------------- prep: W2 rows 1..4096 -> bf16, b2s, W0t, W1t
__global__ __launch_bounds__(256) void prep_kernel(
    const float* __restrict__ W2, const float* __restrict__ b2,
    const float* __restrict__ W0, const float* __restrict__ W1,
    ushort* __restrict__ Bext, float* __restrict__ b2s,
    float* __restrict__ W0t, float* __restrict__ W1t)
{
    const int r = blockIdx.x, t = threadIdx.x;
    Bext[(size_t)r * 256 + t] = f2bf(W2[(size_t)(r + 1) * 256 + t]);
    if (t == 0) b2s[r] = b2[r + 1];
    if (r < 256) W1t[r * 256 + t] = W1[t * 256 + r];
    if (r < 65)  W0t[r * 256 + t] = W0[t * 65 + r];
}

// ---------------------------------------------------------------- MLP layers 0+1 (+ fused kl_target), bf16 t out
__global__ __launch_bounds__(256) void mlp01_kernel(
    const float* __restrict__ x, const float* __restrict__ klb,
    const float* __restrict__ W0t, const float* __restrict__ b0,
    const float* __restrict__ W1t, const float* __restrict__ b1,
    const float* __restrict__ W2, const float* __restrict__ b2,
    const int* __restrict__ AL,
    ushort* __restrict__ t_ext, float* __restrict__ kt)
{
    __shared__ float xk[16][66];
    __shared__ float h0[16][HID];
    __shared__ float ktred[16][4];
    const int tid = threadIdx.x;
    const int lane = tid & 63, w = tid >> 6;
    const int r0 = blockIdx.x * 16;

    for (int f = tid; f < 16 * 64; f += 256) {
        int r = f >> 6, k = f & 63;
        xk[r][k] = x[(size_t)(r0 + r) * 64 + k];
    }
    if (tid < 16) xk[tid][64] = klb[r0 + tid];
    __syncthreads();

    {
        float acc[16];
        float bb = b0[tid];
        #pragma unroll
        for (int r = 0; r < 16; r++) acc[r] = bb;
        for (int k = 0; k < 65; k++) {
            float wv = W0t[k * 256 + tid];
            #pragma unroll
            for (int r = 0; r < 16; r++) acc[r] = fmaf(wv, xk[r][k], acc[r]);
        }
        #pragma unroll
        for (int r = 0; r < 16; r++) h0[r][tid] = fast_tanh(acc[r]);
    }
    __syncthreads();
    {
        float acc[16];
        float bb = b1[tid];
        #pragma unroll
        for (int r = 0; r < 16; r++) acc[r] = bb;
        for (int k = 0; k < HID; k++) {
            float wv = W1t[k * 256 + tid];
            #pragma unroll
            for (int r = 0; r < 16; r++) acc[r] = fmaf(wv, h0[r][k], acc[r]);
        }
        const float w2v = W2[tid];   // W2 row 0
        __syncthreads();
        #pragma unroll
        for (int r = 0; r < 16; r++) {
            float v = fast_tanh(acc[r]);
            t_ext[(size_t)(r0 + r) * 256 + tid] = f2bf(v);
            float p = v * w2v;
            #pragma unroll
            for (int off = 1; off < 64; off <<= 1) p += __shfl_xor(p, off);
            if (lane == 0) ktred[r][w] = p;
        }
        __syncthreads();
        if (tid < 16) {
            float accv = ktred[tid][0] + ktred[tid][1] + ktred[tid][2] + ktred[tid][3];
            float z = accv + b2[0] - logf((float)AL[0]);
            float sg = 1.0f / (1.0f + expf(-z));
            kt[r0 + tid] = sg * klb[r0 + tid] + 1e-6f;
        }
    }
}

// ---------------------------------------------------------------- layer-2 GEMM (bf16 MFMA, K=256), f16 out, XCD swizzle
__global__ __launch_bounds__(256) void gemm2_mfma(
    const ushort* __restrict__ Aext, const ushort* __restrict__ Bext,
    const float* __restrict__ b2s, f16* __restrict__ h2f)
{
    __shared__ ushort As[128 * 64];
    __shared__ ushort Bs[128 * 64];
    const int tid = threadIdx.x;
    const int lane = tid & 63, w = tid >> 6;
    const int bid = blockIdx.y * 32 + blockIdx.x;
    const int swz = (bid & 7) * 256 + (bid >> 3);
    const int m0 = (swz >> 5) * 128, c0 = (swz & 31) * 128;
    const int wm = w & 1, wn = w >> 1;

    f32x4 acc[4][4];
    #pragma unroll
    for (int i = 0; i < 4; i++)
        #pragma unroll
        for (int j = 0; j < 4; j++) acc[i][j] = (f32x4){0.f, 0.f, 0.f, 0.f};

    int sg_row[4], sg_c[4];
    #pragma unroll
    for (int s = 0; s < 4; s++) {
        int idx = (s * 4 + w) * 512 + lane * 8;
        int row = idx >> 6;
        int cp = (idx >> 3) & 7;
        sg_row[s] = row;
        sg_c[s] = cp ^ (row & 7);
    }

    for (int kt = 0; kt < 4; kt++) {
        const int k0 = kt * 64;
        #pragma unroll
        for (int s = 0; s < 4; s++) {
            gload_lds16(&Aext[(size_t)(m0 + sg_row[s]) * 256 + k0 + sg_c[s] * 8],
                        &As[(s * 4 + w) * 512]);
            gload_lds16(&Bext[(size_t)(c0 + sg_row[s]) * 256 + k0 + sg_c[s] * 8],
                        &Bs[(s * 4 + w) * 512]);
        }
        __syncthreads();
        #pragma unroll
        for (int kk = 0; kk < 2; kk++) {
            const int cA = kk * 4 + (lane >> 4);
            bf16x8 af[4], bfr[4];
            #pragma unroll
            for (int i = 0; i < 4; i++) {
                int mr = wm * 64 + i * 16 + (lane & 15);
                af[i] = *(const bf16x8*)&As[mr * 64 + ((cA ^ (mr & 7)) * 8)];
                int nr = wn * 64 + i * 16 + (lane & 15);
                bfr[i] = *(const bf16x8*)&Bs[nr * 64 + ((cA ^ (nr & 7)) * 8)];
            }
            #pragma unroll
            for (int i = 0; i < 4; i++)
                #pragma unroll
                for (int j = 0; j < 4; j++)
                    acc[i][j] = __builtin_amdgcn_mfma_f32_16x16x32_bf16(
                        af[i], bfr[j], acc[i][j], 0, 0, 0);
        }
        __syncthreads();
    }

    const int colb = c0 + wn * 64 + (lane & 15);
    #pragma unroll
    for (int j = 0; j < 4; j++) {
        float bias = b2s[colb + j * 16];
        #pragma unroll
        for (int i = 0; i < 4; i++) {
            int rr = m0 + wm * 64 + i * 16 + (lane >> 4) * 4;
            #pragma unroll
            for (int q = 0; q < 4; q++)
                h2f[(size_t)(rr + q) * 4096 + colb + j * 16] = (f16)(acc[i][j][q] + bias);
        }
    }
}

// ---------------------------------------------------------------- solver: FOUR WAVES PER ROW, 16 elems/thread (f16)
__global__ __launch_bounds__(256) void solve256(
    float* __restrict__ out, const f16* __restrict__ h2f,
    const float* __restrict__ logb, const float* __restrict__ ktarr)
{
    __shared__ float red[16];
    const int tid = threadIdx.x;
    const int lane = tid & 63, w = tid >> 6;
    const int r = blockIdx.x;

    const f16* hrow = h2f + (size_t)r * 4096;
    const float* brow = logb + (size_t)r * 4096;

    f16x4 h4[4];
    f32x4 bv4[4];
    #pragma unroll
    for (int c = 0; c < 4; c++) {
        h4[c] = *(const f16x4*)&hrow[c * 1024 + tid * 4];
        bv4[c] = *(const f32x4*)&brow[c * 1024 + tid * 4];
    }

    float e[16];
    float s = 0.0f, sav = 0.0f;
    #pragma unroll
    for (int c = 0; c < 4; c++)
        #pragma unroll
        for (int j = 0; j < 4; j++) {
            int m = c * 4 + j;
            float av = (float)h4[c][j];
            e[m] = __expf(av + bv4[c][j]);
            s += e[m];
            sav = fmaf(e[m], av, sav);
        }
    #pragma unroll
    for (int off = 1; off < 64; off <<= 1) {
        s   += __shfl_xor(s, off);
        sav += __shfl_xor(sav, off);
    }
    if (lane == 0) { red[w * 2] = s; red[w * 2 + 1] = sav; }
    __syncthreads();
    s   = red[0] + red[2] + red[4] + red[6];
    sav = red[1] + red[3] + red[5] + red[7];

    const float k = ktarr[r];
    const float lns = __logf(s);
    const float inv = 1.0f / s;
    const float kl1 = fmaf(sav, inv, -lns);       // KL(a||b) at alpha=1

    float* orow = out + (size_t)r * 4096;

    if (k >= kl1) {  // fast path: alpha=1, no more barriers
        #pragma unroll
        for (int c = 0; c < 4; c++) {
            f32x4 o;
            #pragma unroll
            for (int j = 0; j < 4; j++) o[j] = e[c * 4 + j] * inv;
            *(f32x4*)&orow[c * 1024 + tid * 4] = o;
        }
        if (tid == 0) {
            float d = kl1 - k;
            out[(size_t)NROWS * NCOL + r] = d * d;
        }
        return;
    }

    // ---------- slow path (~few % of rows) ----------
    float eb[16];
    float c2 = 0.0f, c3 = 0.0f, seb = 0.0f, samv = 0.0f;
    #pragma unroll
    for (int c = 0; c < 4; c++)
        #pragma unroll
        for (int j = 0; j < 4; j++) {
            int m = c * 4 + j;
            float b = bv4[c][j];
            float ebv = __expf(b);
            eb[m] = ebv;
            float a = fmaf(e[m], inv, -ebv);   // amb = ea - eb
            float av = (float)h4[c][j];
            e[m] = a;                          // e[] now holds amb
            c2  = fmaf(ebv, b, c2);            // sum eb*lb
            c3  = fmaf(a, b, c3);              // sum amb*lb
            seb += ebv;
            samv = fmaf(a, av, samv);          // sum amb*av
        }
    #pragma unroll
    for (int off = 1; off < 64; off <<= 1) {
        c2   += __shfl_xor(c2, off);
        c3   += __shfl_xor(c3, off);
        seb  += __shfl_xor(seb, off);
        samv += __shfl_xor(samv, off);
    }
    __syncthreads();
    if (lane == 0) {
        red[w * 4 + 0] = c2;  red[w * 4 + 1] = c3;
        red[w * 4 + 2] = seb; red[w * 4 + 3] = samv;
    }
    __syncthreads();
    c2   = red[0] + red[4] + red[8]  + red[12];
    c3   = red[1] + red[5] + red[9]  + red[13];
    seb  = red[2] + red[6] + red[10] + red[14];
    samv = red[3] + red[7] + red[11] + red[15];

    const float C2 = c2;
    const float C3 = c3;
    const float C4 = (1.0f - seb) - C3;

    float skl = kl1, a_eval = 1.0f;
    float bot = 0.0f, top = 1.0f;
    float d1 = samv - lns * (1.0f - seb) + C4;
    float alpha = fminf(0.5f, fmaxf(1.0f / 16.0f,
                        1.0f + (k - kl1) / (d1 + 1e-12f)));

    for (int it = 1; it < NSTEPS; it++) {
        a_eval = alpha;
        float kacc = 0.0f, dacc = 0.0f;
        #pragma unroll
        for (int m = 0; m < 16; m++) {
            float xv = fmaf(alpha, e[m], eb[m]);
            float lx = __logf(xv);
            kacc = fmaf(xv, lx, kacc);
            dacc = fmaf(e[m], lx, dacc);
        }
        #pragma unroll
        for (int off = 1; off < 64; off <<= 1) {
            kacc += __shfl_xor(kacc, off);
            dacc += __shfl_xor(dacc, off);
        }
        __syncthreads();
        if (lane == 0) { red[w * 2 + 0] = kacc; red[w * 2 + 1] = dacc; }
        __syncthreads();
        kacc = red[0] + red[2] + red[4] + red[6];
        dacc = red[1] + red[3] + red[5] + red[7];

        float klc = kacc - C2 - alpha * C3;
        float dc  = dacc + C4;
        skl = klc;

        bot = (k >= klc) ? alpha : bot;
        top = (k <= klc) ? alpha : top;
        float delta = (k - klc) / (dc + 1e-12f);
        float lo = bot * (15.0f / 16.0f) + top * (1.0f / 16.0f);
        float hi = 0.5f * (bot + top);
        alpha = fminf(hi, fmaxf(lo, alpha + delta));
        if (top - bot < 1e-6f) break;
    }

    if (alpha != a_eval) {
        float kacc = 0.0f;
        #pragma unroll
        for (int m = 0; m < 16; m++) {
            float xv = fmaf(alpha, e[m], eb[m]);
            kacc = fmaf(xv, __logf(xv), kacc);
        }
        #pragma unroll
        for (int off = 1; off < 64; off <<= 1) kacc += __shfl_xor(kacc, off);
        __syncthreads();
        if (lane == 0) red[w] = kacc;
        __syncthreads();
        kacc = red[0] + red[1] + red[2] + red[3];
        skl = kacc - C2 - alpha * C3;
    }

    const float spx = fmaf(alpha, 1.0f - seb, seb);
    const float invs = 1.0f / spx;
    #pragma unroll
    for (int c = 0; c < 4; c++) {
        f32x4 o;
        #pragma unroll
        for (int j = 0; j < 4; j++)
            o[j] = fmaf(alpha, e[c * 4 + j], eb[c * 4 + j]) * invs;
        *(f32x4*)&orow[c * 1024 + tid * 4] = o;
    }
    if (tid == 0) {
        float d = skl - k;
        out[(size_t)NROWS * NCOL + r] = d * d;
    }
}

extern "C" void kernel_launch(void* const* d_in, const int* in_sizes, int n_in,
                              void* d_out, int out_size, void* d_ws, size_t ws_size,
                              hipStream_t stream)
{
    const float* x    = (const float*)d_in[0];
    const float* klb  = (const float*)d_in[1];
    const float* logb = (const float*)d_in[2];
    const float* W0   = (const float*)d_in[3];
    const float* b0   = (const float*)d_in[4];
    const float* W1   = (const float*)d_in[5];
    const float* b1   = (const float*)d_in[6];
    const float* W2   = (const float*)d_in[7];
    const float* b2   = (const float*)d_in[8];
    const int*   AL   = (const int*)d_in[9];
    float* out = (float*)d_out;

    const size_t MB = 1048576ull;
    const size_t KB = 1024ull;
    char* p = (char*)d_ws;
    ushort* tws  = (ushort*)(p);                     // A: 8192*256 bf16 = 4 MB
    ushort* Bext = (ushort*)(p + 4 * MB);            // 4096*256 bf16 = 2 MB
    float*  kt   = (float*) (p + 6 * MB);            // 32 KB
    float*  b2s  = (float*) (p + 6 * MB + 64 * KB);  // 16 KB
    float*  W0t  = (float*) (p + 6 * MB + 128 * KB); // 66.6 KB
    float*  W1t  = (float*) (p + 6 * MB + 256 * KB); // 256 KB
    f16*    h2f  = (f16*)   (p + 8 * MB);            // 64 MB

    hipLaunchKernelGGL(prep_kernel, dim3(4096), dim3(256), 0, stream,
                       W2, b2, W0, W1, Bext, b2s, W0t, W1t);
    hipLaunchKernelGGL(mlp01_kernel, dim3(512), dim3(256), 0, stream,
                       x, klb, W0t, b0, W1t, b1, W2, b2, AL, tws, kt);
    hipLaunchKernelGGL(gemm2_mfma, dim3(32, 64), dim3(256), 0, stream, tws, Bext, b2s, h2f);
    hipLaunchKernelGGL(solve256, dim3(8192), dim3(256), 0, stream, out, h2f, logb, kt);
}